// Round 4
// baseline (4572.248 us; speedup 1.0000x reference)
//
#include <hip/hip_runtime.h>
#include <math.h>

// LSTMPredictor: B=2048 rows, 3x LSTMCell(H=50), P=17, T=512 + 32 future steps.
// fp32 buffers (runtime-sniffed, bf16 fallback kept). One block per CU owns M=8
// batch rows for the whole 544-step recurrence. Weights in per-thread registers:
// thread = (g4 in [0,50), q in [0,8)); g4 owns gates {g4,50+g4,100+g4,150+g4}
// (i,f,g,o bundle -> float4 partials, all-b128 LDS traffic). Each broadcast
// state float4-pair read feeds 32 fmacs. h-state in LDS; c-state in registers.
// __launch_bounds__(512,1): round-3 showed (512,2) => 128-VGPR cap => spill.

#define BATCH    2048
#define PP       17
#define HH       50
#define GG       200      // 4*H
#define MROWS    8
#define NTHREADS 512
#define NBLOCKS  (BATCH / MROWS)   // 256
#define KQ1      9        // cell1 K=68 -> 8 slices of 9 (pad to 72, zero weights)
#define KQ2      13       // cell2 K=100 -> 8 x 13 (pad 104)
#define KQ3      13
#define SROWS    171      // 0..16 x | 17..66 h1 | 67..116 h2 | 117..166 h3 | 167..170 zero pad

__device__ __forceinline__ float bf2f(unsigned short u) {
    unsigned int i = ((unsigned int)u) << 16;
    float f; __builtin_memcpy(&f, &i, 4); return f;
}
__device__ __forceinline__ unsigned short f2bf(float f) {
    unsigned int i; __builtin_memcpy(&i, &f, 4);
    return (unsigned short)((i + 0x7fffu + ((i >> 16) & 1u)) >> 16);
}
__device__ __forceinline__ float ldin(const void* p, long i, bool f32) {
    return f32 ? ((const float*)p)[i] : bf2f(((const unsigned short*)p)[i]);
}
// saturation-safe fast sigmoid/tanh (v_exp_f32 + v_rcp_f32)
__device__ __forceinline__ float fsig(float x) {
    float t = exp2f(-1.44269504089f * x);
    return __builtin_amdgcn_rcpf(1.0f + t);
}
__device__ __forceinline__ float ftanh(float x) {
    float t = exp2f(2.88539008178f * x);
    return 1.0f - 2.0f * __builtin_amdgcn_rcpf(t + 1.0f);
}

// ---- dtype sniffer: bf16 weights decode to |v|<=0.142; fp32-as-bf16 gives junk ----
extern "C" __global__ void sniff_dtype(const unsigned short* __restrict__ w,
                                       int* __restrict__ flag) {
    int lane = threadIdx.x;
    bool bad = false;
#pragma unroll
    for (int t = 0; t < 4; ++t) {
        float v = bf2f(w[lane * 4 + t]);
        bad |= !(fabsf(v) <= 1.0f);
    }
    unsigned long long m = __ballot(bad);
    if (lane == 0) flag[0] = (m != 0ULL) ? 1 : 0;   // 1 => fp32 buffers
}

// gate phase: thread (g4,q) accumulates its K-slice of gates {g4,50+g4,100+g4,150+g4}
// for all 8 rows. Weights in registers; state reads wave-uniform (LDS broadcast).
template <int TQ>
__device__ __forceinline__ void gate_phase(const float* __restrict__ S,
                                           float4* __restrict__ gb4,
                                           const float (&w)[4][TQ],
                                           int srow, int g4, int q, bool act) {
    if (!act) return;
    float a[4][8];
#pragma unroll
    for (int e = 0; e < 4; ++e)
#pragma unroll
        for (int m = 0; m < 8; ++m) a[e][m] = 0.0f;
    const float4* Sp = (const float4*)(S + (srow + q * TQ) * MROWS);
#pragma unroll
    for (int t = 0; t < TQ; ++t) {
        float4 lo = Sp[2 * t];        // wave-uniform -> broadcast
        float4 hi = Sp[2 * t + 1];
#pragma unroll
        for (int e = 0; e < 4; ++e) {
            float wv = w[e][t];
            a[e][0] = fmaf(wv, lo.x, a[e][0]); a[e][1] = fmaf(wv, lo.y, a[e][1]);
            a[e][2] = fmaf(wv, lo.z, a[e][2]); a[e][3] = fmaf(wv, lo.w, a[e][3]);
            a[e][4] = fmaf(wv, hi.x, a[e][4]); a[e][5] = fmaf(wv, hi.y, a[e][5]);
            a[e][6] = fmaf(wv, hi.z, a[e][6]); a[e][7] = fmaf(wv, hi.w, a[e][7]);
        }
    }
#pragma unroll
    for (int m = 0; m < 8; ++m) {     // contiguous b128 stores (lanes consecutive)
        float4 v; v.x = a[0][m]; v.y = a[1][m]; v.z = a[2][m]; v.w = a[3][m];
        gb4[(q * MROWS + m) * HH + g4] = v;
    }
}

__device__ __forceinline__ void lstm_update(float* __restrict__ S,
                                            const float4* __restrict__ gb4,
                                            const float4* __restrict__ bsv,
                                            float& c, int hrow, int tid) {
    // caller guards tid < 400;  m = tid&7 (conflict-free h write), j = tid>>3
    int m = tid & 7;
    int j = tid >> 3;
    float4 s = bsv[j];                // (i,f,g,o) combined bias
#pragma unroll
    for (int q = 0; q < 8; ++q) {
        float4 v = gb4[(q * MROWS + m) * HH + j];
        s.x += v.x; s.y += v.y; s.z += v.z; s.w += v.w;
    }
    float cn = fsig(s.y) * c + fsig(s.x) * ftanh(s.z);
    c = cn;
    S[(hrow + j) * MROWS + m] = fsig(s.w) * ftanh(cn);
}

extern "C" __global__ void __launch_bounds__(NTHREADS, 1)
lstm_persistent(const void* __restrict__ x,
                const void* __restrict__ wih1, const void* __restrict__ whh1,
                const void* __restrict__ bih1, const void* __restrict__ bhh1,
                const void* __restrict__ wih2, const void* __restrict__ whh2,
                const void* __restrict__ bih2, const void* __restrict__ bhh2,
                const void* __restrict__ wih3, const void* __restrict__ whh3,
                const void* __restrict__ bih3, const void* __restrict__ bhh3,
                const void* __restrict__ wlin, const void* __restrict__ blin,
                void* __restrict__ out, const int* __restrict__ flag,
                int T, int steps)
{
    const int tid = threadIdx.x;
    __shared__ float  S[SROWS * MROWS];        // 5.5 KB
    __shared__ float4 gb4[8 * MROWS * HH];     // 51.2 KB  [q][m][j] -> (i,f,g,o)
    __shared__ float4 bsv[3][HH];              // 2.4 KB
    __shared__ float  WLt[PP][52];             // 3.5 KB   [p][k], k 50,51 zero
    __shared__ float  bl[PP];

    const bool f32 = (flag[0] != 0);

    const int lane = tid & 63;
    const int q    = tid >> 6;                 // wave-uniform K-slice
    const int g4   = lane;                     // hidden idx; active if < 50
    const bool act = (lane < HH);

    // ---- per-thread register weights (fp32, full precision) ----
    float w1[4][KQ1], w2[4][KQ2], w3[4][KQ3];
    if (act) {
#pragma unroll
        for (int e = 0; e < 4; ++e) {
            const int g = e * HH + g4;
#pragma unroll
            for (int t = 0; t < KQ1; ++t) {
                int k = q * KQ1 + t;
                w1[e][t] = (k < 17) ? ldin(wih1, (long)g * 17 + k, f32)
                         : (k < 67) ? ldin(whh1, (long)g * 50 + (k - 17), f32)
                                    : 0.0f;
            }
#pragma unroll
            for (int t = 0; t < KQ2; ++t) {
                int k = q * KQ2 + t;
                w2[e][t] = (k < 50)  ? ldin(wih2, (long)g * 50 + k, f32)
                         : (k < 100) ? ldin(whh2, (long)g * 50 + (k - 50), f32)
                                     : 0.0f;
            }
#pragma unroll
            for (int t = 0; t < KQ3; ++t) {
                int k = q * KQ3 + t;
                w3[e][t] = (k < 50)  ? ldin(wih3, (long)g * 50 + k, f32)
                         : (k < 100) ? ldin(whh3, (long)g * 50 + (k - 50), f32)
                                     : 0.0f;
            }
        }
    }

    // ---- stage biases (i,f,g,o float4), W_lin^T, zero h+pad, preload x(0) ----
    if (tid < 150) {
        int cc = tid / HH, j = tid - cc * HH;
        const void* bi = (cc == 0) ? bih1 : (cc == 1) ? bih2 : bih3;
        const void* bh = (cc == 0) ? bhh1 : (cc == 1) ? bhh2 : bhh3;
        float4 v;
        v.x = ldin(bi, j,       f32) + ldin(bh, j,       f32);
        v.y = ldin(bi, 50 + j,  f32) + ldin(bh, 50 + j,  f32);
        v.z = ldin(bi, 100 + j, f32) + ldin(bh, 100 + j, f32);
        v.w = ldin(bi, 150 + j, f32) + ldin(bh, 150 + j, f32);
        bsv[cc][j] = v;
    } else if (tid < 150 + PP) {
        bl[tid - 150] = ldin(blin, tid - 150, f32);
    }
    for (int i = tid; i < PP * 52; i += NTHREADS) {
        int p = i / 52, k = i - p * 52;
        WLt[p][k] = (k < 50) ? ldin(wlin, (long)p * 50 + k, f32) : 0.0f;
    }
    for (int i = tid; i < SROWS * MROWS - 136; i += NTHREADS) S[136 + i] = 0.0f;

    const long rowBase = (long)blockIdx.x * MROWS;
    const long xStride = (long)T * PP;
    if (tid < 136) {
        int m = tid / PP, p = tid - (tid / PP) * PP;
        S[p * MROWS + m] = ldin(x, (rowBase + m) * xStride + p, f32);
    }
    float c1 = 0.0f, c2 = 0.0f, c3 = 0.0f;
    __syncthreads();

    const long outStride = (long)steps * PP;
    for (int s = 0; s < steps; ++s) {
        // early-issue next-step x loads from gate-idle lanes (latency hidden
        // behind all 6 gate/update phases; committed to LDS in phase 7)
        float xp0 = 0.0f, xp1 = 0.0f;
        int u0 = 136, u1 = 136;
        if (lane >= HH && s + 1 < T) {
            int idx = q * 14 + (lane - HH);          // 0..111
            u0 = idx; u1 = idx + 112;
            if (u0 < 136)
                xp0 = ldin(x, (rowBase + u0 / PP) * xStride + (long)(s + 1) * PP + (u0 % PP), f32);
            if (u1 < 136)
                xp1 = ldin(x, (rowBase + u1 / PP) * xStride + (long)(s + 1) * PP + (u1 % PP), f32);
        }

        gate_phase<KQ1>(S, gb4, w1, 0, g4, q, act);            // cell1: [x|h1]
        __syncthreads();
        if (tid < 400) lstm_update(S, gb4, bsv[0], c1, 17, tid);
        __syncthreads();
        gate_phase<KQ2>(S, gb4, w2, 17, g4, q, act);           // cell2: [h1|h2]
        __syncthreads();
        if (tid < 400) lstm_update(S, gb4, bsv[1], c2, 67, tid);
        __syncthreads();
        gate_phase<KQ3>(S, gb4, w3, 67, g4, q, act);           // cell3: [h2|h3]
        __syncthreads();
        if (tid < 400) lstm_update(S, gb4, bsv[2], c3, 117, tid);
        __syncthreads();
        // ---- linear head + output + next input (feedback or prefetched x) ----
        if (tid < 136) {
            int m = tid / PP, p = tid - (tid / PP) * PP;
            float acc = bl[p];
            const float4* wp = (const float4*)(&WLt[p][0]);
#pragma unroll
            for (int kk = 0; kk < 13; ++kk) {       // k 50..51: zero W x zero S pad
                float4 wv = wp[kk];
                int k = 4 * kk;
                acc = fmaf(wv.x, S[(117 + k) * MROWS + m], acc);
                acc = fmaf(wv.y, S[(118 + k) * MROWS + m], acc);
                acc = fmaf(wv.z, S[(119 + k) * MROWS + m], acc);
                acc = fmaf(wv.w, S[(120 + k) * MROWS + m], acc);
            }
            long oi = (rowBase + m) * outStride + (long)s * PP + p;
            if (f32) ((float*)out)[oi] = acc;
            else     ((unsigned short*)out)[oi] = f2bf(acc);
            if (s + 1 >= T && s + 1 < steps)        // autoregressive feedback
                S[p * MROWS + m] = acc;
        }
        if (lane >= HH && s + 1 < T) {              // commit prefetched x
            if (u0 < 136) S[(u0 % PP) * MROWS + (u0 / PP)] = xp0;
            if (u1 < 136) S[(u1 % PP) * MROWS + (u1 / PP)] = xp1;
        }
        __syncthreads();
    }
}

extern "C" void kernel_launch(void* const* d_in, const int* in_sizes, int n_in,
                              void* d_out, int out_size, void* d_ws, size_t ws_size,
                              hipStream_t stream) {
    (void)ws_size; (void)n_in;
    int* flag = (int*)d_ws;

    const int T     = in_sizes[0] / (BATCH * PP);   // 512
    const int steps = out_size / (BATCH * PP);      // 544

    sniff_dtype<<<1, 64, 0, stream>>>((const unsigned short*)d_in[1], flag);

    lstm_persistent<<<NBLOCKS, NTHREADS, 0, stream>>>(
        d_in[0],
        d_in[1], d_in[2], d_in[3], d_in[4],
        d_in[5], d_in[6], d_in[7], d_in[8],
        d_in[9], d_in[10], d_in[11], d_in[12],
        d_in[13], d_in[14],
        d_out, flag, T, steps);
}